// Round 6
// baseline (166.427 us; speedup 1.0000x reference)
//
#include <hip/hip_runtime.h>

#define N 1024
#define D 128

// ---------------- proj: Q,K,A,B = z@{Wq,Wk,W1a,W1b} (+biases; b1 folded into A; 1/sqrt(D) folded into Q) ----------------
__global__ __launch_bounds__(256) void proj_kernel(
    const float* __restrict__ z,
    const float* __restrict__ Wq, const float* __restrict__ bq,
    const float* __restrict__ Wk, const float* __restrict__ bk,
    const float* __restrict__ W1, const float* __restrict__ b1,
    float* __restrict__ Q, float* __restrict__ Kx,
    float* __restrict__ A, float* __restrict__ B)
{
    const int d  = threadIdx.x & (D - 1);
    const int h  = threadIdx.x >> 7;              // wave-uniform: 0 -> Q/K, 1 -> A/B
    const int r0 = blockIdx.x * 8;
    const float* __restrict__ Wa = h ? W1           : Wq;
    const float* __restrict__ Wb = h ? (W1 + D * D) : Wk;

    float acc0[8] = {0,0,0,0,0,0,0,0};
    float acc1[8] = {0,0,0,0,0,0,0,0};

    for (int c = 0; c < D / 4; ++c) {
        float4 zr[8];
#pragma unroll
        for (int r = 0; r < 8; ++r)
            zr[r] = *(const float4*)&z[(r0 + r) * D + c * 4];   // uniform addr -> scalar loads
#pragma unroll
        for (int q = 0; q < 4; ++q) {
            const int k = c * 4 + q;
            const float wa = Wa[k * D + d];
            const float wb = Wb[k * D + d];
#pragma unroll
            for (int r = 0; r < 8; ++r) {
                const float zv = (q == 0) ? zr[r].x : (q == 1) ? zr[r].y : (q == 2) ? zr[r].z : zr[r].w;
                acc0[r] = fmaf(zv, wa, acc0[r]);
                acc1[r] = fmaf(zv, wb, acc1[r]);
            }
        }
    }
    if (h == 0) {
        const float c0 = bq[d], c1 = bk[d];
        const float scale = 0.08838834764831845f;   // 1/sqrt(128), folded into Q
#pragma unroll
        for (int r = 0; r < 8; ++r) {
            Q [(r0 + r) * D + d] = (acc0[r] + c0) * scale;
            Kx[(r0 + r) * D + d] = acc1[r] + c1;
        }
    } else {
        const float c0 = b1[d];
#pragma unroll
        for (int r = 0; r < 8; ++r) {
            A[(r0 + r) * D + d] = acc0[r] + c0;
            B[(r0 + r) * D + d] = acc1[r];
        }
    }
}

// ---------------- scores: S = (Q K^T) * exp(-dist), 32x32 tile ----------------
__global__ __launch_bounds__(256) void score_kernel(
    const float* __restrict__ Q, const float* __restrict__ Kx,
    const float* __restrict__ dist, float* __restrict__ S)
{
    __shared__ float Qs[32 * 33 * 4];
    __shared__ float Ks[32 * 33 * 4];
    const int tid = threadIdx.x;
    const int bi = blockIdx.y * 32, bj = blockIdx.x * 32;
    const int tx = tid & 15, ty = tid >> 4;

#pragma unroll
    for (int t = 0; t < 4; ++t) {
        const int e = t * 256 + tid;           // 1024 chunks: 32 rows x 32 float4-cols
        const int row = e >> 5, c = e & 31;
        *(float4*)&Qs[(row * 33 + c) * 4] = *(const float4*)&Q [(size_t)(bi + row) * D + c * 4];
        *(float4*)&Ks[(row * 33 + c) * 4] = *(const float4*)&Kx[(size_t)(bj + row) * D + c * 4];
    }
    __syncthreads();

    const float4* Qs4 = (const float4*)Qs;
    const float4* Ks4 = (const float4*)Ks;
    float a00 = 0.f, a01 = 0.f, a10 = 0.f, a11 = 0.f;

#pragma unroll 4
    for (int c = 0; c < 32; ++c) {
        const float4 q0 = Qs4[ty * 33 + c];
        const float4 q1 = Qs4[(ty + 16) * 33 + c];
        const float4 k0 = Ks4[tx * 33 + c];
        const float4 k1 = Ks4[(tx + 16) * 33 + c];
        a00 = fmaf(q0.x, k0.x, a00); a00 = fmaf(q0.y, k0.y, a00); a00 = fmaf(q0.z, k0.z, a00); a00 = fmaf(q0.w, k0.w, a00);
        a01 = fmaf(q0.x, k1.x, a01); a01 = fmaf(q0.y, k1.y, a01); a01 = fmaf(q0.z, k1.z, a01); a01 = fmaf(q0.w, k1.w, a01);
        a10 = fmaf(q1.x, k0.x, a10); a10 = fmaf(q1.y, k0.y, a10); a10 = fmaf(q1.z, k0.z, a10); a10 = fmaf(q1.w, k0.w, a10);
        a11 = fmaf(q1.x, k1.x, a11); a11 = fmaf(q1.y, k1.y, a11); a11 = fmaf(q1.z, k1.z, a11); a11 = fmaf(q1.w, k1.w, a11);
    }

    const int i0 = bi + ty, i1 = bi + ty + 16;
    const int j0 = bj + tx, j1 = bj + tx + 16;
    S[(size_t)i0 * N + j0] = a00 * __expf(-dist[(size_t)i0 * N + j0]);
    S[(size_t)i0 * N + j1] = a01 * __expf(-dist[(size_t)i0 * N + j1]);
    S[(size_t)i1 * N + j0] = a10 * __expf(-dist[(size_t)i1 * N + j0]);
    S[(size_t)i1 * N + j1] = a11 * __expf(-dist[(size_t)i1 * N + j1]);
}

// ---------------- softmax + top-32 per row; one wave per row, no barriers ----------------
__global__ __launch_bounds__(256) void topk_kernel(float* buf /* in: scores, out: adjacency (in-place) */)
{
    const int lane = threadIdx.x & 63;
    const int row  = blockIdx.x * 4 + (threadIdx.x >> 6);
    float* sr = buf + (size_t)row * N;

    float v[16];
#pragma unroll
    for (int c = 0; c < 4; ++c) {
        const float4 f = *(const float4*)&sr[(c * 64 + lane) * 4];
        v[c * 4 + 0] = f.x; v[c * 4 + 1] = f.y; v[c * 4 + 2] = f.z; v[c * 4 + 3] = f.w;
    }
    float m = v[0];
#pragma unroll
    for (int e = 1; e < 16; ++e) m = fmaxf(m, v[e]);
#pragma unroll
    for (int off = 1; off < 64; off <<= 1) m = fmaxf(m, __shfl_xor(m, off));
    float sum = 0.f;
#pragma unroll
    for (int e = 0; e < 16; ++e) sum += __expf(v[e] - m);
#pragma unroll
    for (int off = 1; off < 64; off <<= 1) sum += __shfl_xor(sum, off);
    const float inv = 1.0f / sum;

    // 64-bit keys: monotonic-float high word, inverted index low word (ties -> smallest j, = lax.top_k)
    unsigned long long key[16];
#pragma unroll
    for (int e = 0; e < 16; ++e) {
        const int j = (((e >> 2) * 64 + lane) * 4) + (e & 3);
        unsigned u = __float_as_uint(v[e]);
        u = (u & 0x80000000u) ? ~u : (u | 0x80000000u);
        key[e] = ((unsigned long long)u << 32) | (unsigned)(N - 1 - j);
    }
    unsigned flags = 0;
    for (int it = 0; it < 32; ++it) {
        unsigned long long best = key[0];
#pragma unroll
        for (int e = 1; e < 16; ++e) best = (key[e] > best) ? key[e] : best;
#pragma unroll
        for (int off = 1; off < 64; off <<= 1) {
            const unsigned long long o = __shfl_xor(best, off);
            if (o > best) best = o;
        }
#pragma unroll
        for (int e = 0; e < 16; ++e)
            if (key[e] == best) { flags |= 1u << e; key[e] = 0ull; }
    }
#pragma unroll
    for (int c = 0; c < 4; ++c) {
        float4 o;
        o.x = (flags & (1u << (c * 4 + 0))) ? __expf(v[c * 4 + 0] - m) * inv : 0.f;
        o.y = (flags & (1u << (c * 4 + 1))) ? __expf(v[c * 4 + 1] - m) * inv : 0.f;
        o.z = (flags & (1u << (c * 4 + 2))) ? __expf(v[c * 4 + 2] - m) * inv : 0.f;
        o.w = (flags & (1u << (c * 4 + 3))) ? __expf(v[c * 4 + 3] - m) * inv : 0.f;
        *(float4*)&sr[(c * 64 + lane) * 4] = o;
    }
}

// ---------------- pairwise gelu classifier + 3-way softmax ----------------
// 64x64 tile, 4x4 micro-tile, TRANSPOSED LDS [d][i] pitch 65:
//  - one ds_read_b128 = 4 i (or j) values at fixed d -> 2 LDS insts per 16 gelu sites
//  - LDS addr = base + d*260 -> pure immediate offsets, zero address math in loop
//  - W2 via wave-uniform scalar loads (K$), off the LDS pipe
__device__ __forceinline__ float fast_gelu(float x) {
    // x * sigmoid(1.5957691*x + 0.0713548*x^3) in exp2 form; max |err| vs exact gelu ~3e-4
    const float u = x * x;
    const float t = x * fmaf(-0.1029434f, u, -2.3022082f);
    return x * __builtin_amdgcn_rcpf(1.0f + __builtin_amdgcn_exp2f(t));
}

#define PITCH 65

__global__ __launch_bounds__(256, 1) void pair_kernel(
    const float* __restrict__ A, const float* __restrict__ B,
    const float* __restrict__ W2, const float* __restrict__ b2,
    float* __restrict__ out)
{
    __shared__ float As[D * PITCH];    // [d][i], 64 i-rows of this tile
    __shared__ float Bs[D * PITCH];    // [d][j]
    const int tid = threadIdx.x;
    const int bi = blockIdx.y * 64, bj = blockIdx.x * 64;
    const int tj = tid & 15, ti = tid >> 4;      // 16 x 16 threads
    const int ai = 4 * ti, aj = 4 * tj;

    // staging: transpose 64x128 -> [d][row]; coalesced global float4 reads, 4x ds_write_b32
#pragma unroll
    for (int p = 0; p < 8; ++p) {
        const int row = p * 8 + (tid >> 5);
        const int c   = tid & 31;
        const float4 av = *(const float4*)&A[(size_t)(bi + row) * D + c * 4];
        const float4 bv = *(const float4*)&B[(size_t)(bj + row) * D + c * 4];
        As[(c * 4 + 0) * PITCH + row] = av.x;
        As[(c * 4 + 1) * PITCH + row] = av.y;
        As[(c * 4 + 2) * PITCH + row] = av.z;
        As[(c * 4 + 3) * PITCH + row] = av.w;
        Bs[(c * 4 + 0) * PITCH + row] = bv.x;
        Bs[(c * 4 + 1) * PITCH + row] = bv.y;
        Bs[(c * 4 + 2) * PITCH + row] = bv.z;
        Bs[(c * 4 + 3) * PITCH + row] = bv.w;
    }
    const float bb0 = b2[0], bb1 = b2[1], bb2 = b2[2];
    __syncthreads();

    float acc[16][3];
#pragma unroll
    for (int s = 0; s < 16; ++s) { acc[s][0] = bb0; acc[s][1] = bb1; acc[s][2] = bb2; }

#pragma unroll 4
    for (int d = 0; d < D; ++d) {
        const float4 av = *(const float4*)&As[d * PITCH + ai];
        const float4 bv = *(const float4*)&Bs[d * PITCH + aj];
        const float w0 = W2[d * 3 + 0];          // uniform -> s_load
        const float w1 = W2[d * 3 + 1];
        const float w2 = W2[d * 3 + 2];
        const float ax[4] = {av.x, av.y, av.z, av.w};
        const float bx[4] = {bv.x, bv.y, bv.z, bv.w};
#pragma unroll
        for (int ii = 0; ii < 4; ++ii)
#pragma unroll
            for (int jj = 0; jj < 4; ++jj) {
                const float g = fast_gelu(ax[ii] + bx[jj]);
                float* l = acc[ii * 4 + jj];
                l[0] = fmaf(g, w0, l[0]);
                l[1] = fmaf(g, w1, l[1]);
                l[2] = fmaf(g, w2, l[2]);
            }
    }

#pragma unroll
    for (int ii = 0; ii < 4; ++ii) {
        const int i = bi + ai + ii;
        float tmp[12];
#pragma unroll
        for (int jj = 0; jj < 4; ++jj) {
            const float* l = acc[ii * 4 + jj];
            const float mm = fmaxf(l[0], fmaxf(l[1], l[2]));
            const float e0 = __expf(l[0] - mm), e1 = __expf(l[1] - mm), e2 = __expf(l[2] - mm);
            const float iv = 1.0f / (e0 + e1 + e2);
            tmp[jj * 3 + 0] = e0 * iv;
            tmp[jj * 3 + 1] = e1 * iv;
            tmp[jj * 3 + 2] = e2 * iv;
        }
        float* o = out + ((size_t)i * N + bj + aj) * 3;   // 12 consecutive floats, 16B-aligned
        *(float4*)&o[0] = *(const float4*)&tmp[0];
        *(float4*)&o[4] = *(const float4*)&tmp[4];
        *(float4*)&o[8] = *(const float4*)&tmp[8];
    }
}

extern "C" void kernel_launch(void* const* d_in, const int* in_sizes, int n_in,
                              void* d_out, int out_size, void* d_ws, size_t ws_size,
                              hipStream_t stream)
{
    const float* z    = (const float*)d_in[0];
    const float* dist = (const float*)d_in[1];
    const float* Wq   = (const float*)d_in[2];
    const float* bq   = (const float*)d_in[3];
    const float* Wk   = (const float*)d_in[4];
    const float* bk   = (const float*)d_in[5];
    const float* W1   = (const float*)d_in[6];
    const float* b1   = (const float*)d_in[7];
    const float* W2   = (const float*)d_in[8];
    const float* b2   = (const float*)d_in[9];

    float* out = (float*)d_out;
    float* ws  = (float*)d_ws;
    float* Q  = ws;
    float* K  = ws + (size_t)N * D;
    float* A  = ws + 2 * (size_t)N * D;
    float* B  = ws + 3 * (size_t)N * D;

    proj_kernel<<<N / 8, 256, 0, stream>>>(z, Wq, bq, Wk, bk, W1, b1, Q, K, A, B);
    score_kernel<<<dim3(N / 32, N / 32), 256, 0, stream>>>(Q, K, dist, out);
    topk_kernel<<<N / 4, 256, 0, stream>>>(out);
    pair_kernel<<<dim3(N / 64, N / 64), 256, 0, stream>>>(A, B, W2, b2, out + (size_t)N * N);
}

// Round 7
// 164.755 us; speedup vs baseline: 1.0101x; 1.0101x over previous
//
#include <hip/hip_runtime.h>

#define N 1024
#define D 128

// ---------------- proj: Q,K,A,B = z@{Wq,Wk,W1a,W1b} (+biases; b1 folded into A; 1/sqrt(D) folded into Q) ----------------
__global__ __launch_bounds__(256) void proj_kernel(
    const float* __restrict__ z,
    const float* __restrict__ Wq, const float* __restrict__ bq,
    const float* __restrict__ Wk, const float* __restrict__ bk,
    const float* __restrict__ W1, const float* __restrict__ b1,
    float* __restrict__ Q, float* __restrict__ Kx,
    float* __restrict__ A, float* __restrict__ B)
{
    const int d  = threadIdx.x & (D - 1);
    const int h  = threadIdx.x >> 7;              // wave-uniform: 0 -> Q/K, 1 -> A/B
    const int r0 = blockIdx.x * 8;
    const float* __restrict__ Wa = h ? W1           : Wq;
    const float* __restrict__ Wb = h ? (W1 + D * D) : Wk;

    float acc0[8] = {0,0,0,0,0,0,0,0};
    float acc1[8] = {0,0,0,0,0,0,0,0};

    for (int c = 0; c < D / 4; ++c) {
        float4 zr[8];
#pragma unroll
        for (int r = 0; r < 8; ++r)
            zr[r] = *(const float4*)&z[(r0 + r) * D + c * 4];   // uniform addr -> scalar loads
#pragma unroll
        for (int q = 0; q < 4; ++q) {
            const int k = c * 4 + q;
            const float wa = Wa[k * D + d];
            const float wb = Wb[k * D + d];
#pragma unroll
            for (int r = 0; r < 8; ++r) {
                const float zv = (q == 0) ? zr[r].x : (q == 1) ? zr[r].y : (q == 2) ? zr[r].z : zr[r].w;
                acc0[r] = fmaf(zv, wa, acc0[r]);
                acc1[r] = fmaf(zv, wb, acc1[r]);
            }
        }
    }
    if (h == 0) {
        const float c0 = bq[d], c1 = bk[d];
        const float scale = 0.08838834764831845f;   // 1/sqrt(128), folded into Q
#pragma unroll
        for (int r = 0; r < 8; ++r) {
            Q [(r0 + r) * D + d] = (acc0[r] + c0) * scale;
            Kx[(r0 + r) * D + d] = acc1[r] + c1;
        }
    } else {
        const float c0 = b1[d];
#pragma unroll
        for (int r = 0; r < 8; ++r) {
            A[(r0 + r) * D + d] = acc0[r] + c0;
            B[(r0 + r) * D + d] = acc1[r];
        }
    }
}

// ---------------- scores: S = (Q K^T) * exp(-dist), 32x32 tile ----------------
__global__ __launch_bounds__(256) void score_kernel(
    const float* __restrict__ Q, const float* __restrict__ Kx,
    const float* __restrict__ dist, float* __restrict__ S)
{
    __shared__ float Qs[32 * 33 * 4];
    __shared__ float Ks[32 * 33 * 4];
    const int tid = threadIdx.x;
    const int bi = blockIdx.y * 32, bj = blockIdx.x * 32;
    const int tx = tid & 15, ty = tid >> 4;

#pragma unroll
    for (int t = 0; t < 4; ++t) {
        const int e = t * 256 + tid;           // 1024 chunks: 32 rows x 32 float4-cols
        const int row = e >> 5, c = e & 31;
        *(float4*)&Qs[(row * 33 + c) * 4] = *(const float4*)&Q [(size_t)(bi + row) * D + c * 4];
        *(float4*)&Ks[(row * 33 + c) * 4] = *(const float4*)&Kx[(size_t)(bj + row) * D + c * 4];
    }
    __syncthreads();

    const float4* Qs4 = (const float4*)Qs;
    const float4* Ks4 = (const float4*)Ks;
    float a00 = 0.f, a01 = 0.f, a10 = 0.f, a11 = 0.f;

#pragma unroll 4
    for (int c = 0; c < 32; ++c) {
        const float4 q0 = Qs4[ty * 33 + c];
        const float4 q1 = Qs4[(ty + 16) * 33 + c];
        const float4 k0 = Ks4[tx * 33 + c];
        const float4 k1 = Ks4[(tx + 16) * 33 + c];
        a00 = fmaf(q0.x, k0.x, a00); a00 = fmaf(q0.y, k0.y, a00); a00 = fmaf(q0.z, k0.z, a00); a00 = fmaf(q0.w, k0.w, a00);
        a01 = fmaf(q0.x, k1.x, a01); a01 = fmaf(q0.y, k1.y, a01); a01 = fmaf(q0.z, k1.z, a01); a01 = fmaf(q0.w, k1.w, a01);
        a10 = fmaf(q1.x, k0.x, a10); a10 = fmaf(q1.y, k0.y, a10); a10 = fmaf(q1.z, k0.z, a10); a10 = fmaf(q1.w, k0.w, a10);
        a11 = fmaf(q1.x, k1.x, a11); a11 = fmaf(q1.y, k1.y, a11); a11 = fmaf(q1.z, k1.z, a11); a11 = fmaf(q1.w, k1.w, a11);
    }

    const int i0 = bi + ty, i1 = bi + ty + 16;
    const int j0 = bj + tx, j1 = bj + tx + 16;
    S[(size_t)i0 * N + j0] = a00 * __expf(-dist[(size_t)i0 * N + j0]);
    S[(size_t)i0 * N + j1] = a01 * __expf(-dist[(size_t)i0 * N + j1]);
    S[(size_t)i1 * N + j0] = a10 * __expf(-dist[(size_t)i1 * N + j0]);
    S[(size_t)i1 * N + j1] = a11 * __expf(-dist[(size_t)i1 * N + j1]);
}

// ---------------- softmax + top-32 per row; one wave per row, no barriers ----------------
__global__ __launch_bounds__(256) void topk_kernel(float* buf /* in: scores, out: adjacency (in-place) */)
{
    const int lane = threadIdx.x & 63;
    const int row  = blockIdx.x * 4 + (threadIdx.x >> 6);
    float* sr = buf + (size_t)row * N;

    float v[16];
#pragma unroll
    for (int c = 0; c < 4; ++c) {
        const float4 f = *(const float4*)&sr[(c * 64 + lane) * 4];
        v[c * 4 + 0] = f.x; v[c * 4 + 1] = f.y; v[c * 4 + 2] = f.z; v[c * 4 + 3] = f.w;
    }
    float m = v[0];
#pragma unroll
    for (int e = 1; e < 16; ++e) m = fmaxf(m, v[e]);
#pragma unroll
    for (int off = 1; off < 64; off <<= 1) m = fmaxf(m, __shfl_xor(m, off));
    float sum = 0.f;
#pragma unroll
    for (int e = 0; e < 16; ++e) sum += __expf(v[e] - m);
#pragma unroll
    for (int off = 1; off < 64; off <<= 1) sum += __shfl_xor(sum, off);
    const float inv = 1.0f / sum;

    // 64-bit keys: monotonic-float high word, inverted index low word (ties -> smallest j, = lax.top_k)
    unsigned long long key[16];
#pragma unroll
    for (int e = 0; e < 16; ++e) {
        const int j = (((e >> 2) * 64 + lane) * 4) + (e & 3);
        unsigned u = __float_as_uint(v[e]);
        u = (u & 0x80000000u) ? ~u : (u | 0x80000000u);
        key[e] = ((unsigned long long)u << 32) | (unsigned)(N - 1 - j);
    }
    unsigned flags = 0;
    for (int it = 0; it < 32; ++it) {
        unsigned long long best = key[0];
#pragma unroll
        for (int e = 1; e < 16; ++e) best = (key[e] > best) ? key[e] : best;
#pragma unroll
        for (int off = 1; off < 64; off <<= 1) {
            const unsigned long long o = __shfl_xor(best, off);
            if (o > best) best = o;
        }
#pragma unroll
        for (int e = 0; e < 16; ++e)
            if (key[e] == best) { flags |= 1u << e; key[e] = 0ull; }
    }
#pragma unroll
    for (int c = 0; c < 4; ++c) {
        float4 o;
        o.x = (flags & (1u << (c * 4 + 0))) ? __expf(v[c * 4 + 0] - m) * inv : 0.f;
        o.y = (flags & (1u << (c * 4 + 1))) ? __expf(v[c * 4 + 1] - m) * inv : 0.f;
        o.z = (flags & (1u << (c * 4 + 2))) ? __expf(v[c * 4 + 2] - m) * inv : 0.f;
        o.w = (flags & (1u << (c * 4 + 3))) ? __expf(v[c * 4 + 3] - m) * inv : 0.f;
        *(float4*)&sr[(c * 64 + lane) * 4] = o;
    }
}

// ---------------- pairwise gelu classifier + 3-way softmax ----------------
// 32x32 tile, 2x2 micro-tile, d-SPLIT staging: only 64 of 128 d's resident -> LDS 17.4 KB
// -> high occupancy (r3 evidence: perf tracks occupancy, not LDS-reads/eval).
// Layout [row][d-chunk] pitch 17 float4s: b128 reads, 2-way aliasing only (free), 0 conflicts.
__device__ __forceinline__ float fast_gelu(float x) {
    // x * sigmoid(1.5957691*x + 0.0713548*x^3) in exp2 form; max |err| vs exact gelu ~3e-4
    const float u = x * x;
    const float t = x * fmaf(-0.1029434f, u, -2.3022082f);
    return x * __builtin_amdgcn_rcpf(1.0f + __builtin_amdgcn_exp2f(t));
}

__global__ __launch_bounds__(256) void pair_kernel(
    const float* __restrict__ A, const float* __restrict__ B,
    const float* __restrict__ W2, const float* __restrict__ b2,
    float* __restrict__ out)
{
    __shared__ float As[32 * 17 * 4];   // [row][chunk] pitch 17 float4 = 68 floats
    __shared__ float Bs[32 * 17 * 4];
    const int tid = threadIdx.x;
    const int bi = blockIdx.y * 32, bj = blockIdx.x * 32;
    const int tx = tid & 15, ty = tid >> 4;

    const float bb0 = b2[0], bb1 = b2[1], bb2 = b2[2];
    float l[4][3];
#pragma unroll
    for (int p = 0; p < 4; ++p) { l[p][0] = bb0; l[p][1] = bb1; l[p][2] = bb2; }

    const float4* As4 = (const float4*)As;
    const float4* Bs4 = (const float4*)Bs;

    for (int kk = 0; kk < D; kk += 64) {
        __syncthreads();               // protect LDS from previous stage's readers
#pragma unroll
        for (int t = 0; t < 2; ++t) {
            const int e = t * 256 + tid;       // 512 chunks: 32 rows x 16 float4-cols
            const int row = e >> 4, c = e & 15;
            *(float4*)&As[(row * 17 + c) * 4] = *(const float4*)&A[(size_t)(bi + row) * D + kk + c * 4];
            *(float4*)&Bs[(row * 17 + c) * 4] = *(const float4*)&B[(size_t)(bj + row) * D + kk + c * 4];
        }
        __syncthreads();

#pragma unroll 4
        for (int c = 0; c < 16; ++c) {
            const float4 a0 = As4[ty * 17 + c];
            const float4 a1 = As4[(ty + 16) * 17 + c];
            const float4 b0 = Bs4[tx * 17 + c];
            const float4 b1 = Bs4[(tx + 16) * 17 + c];
#pragma unroll
            for (int q = 0; q < 4; ++q) {
                const int dd = kk + c * 4 + q;
                const float w0 = W2[dd * 3 + 0];    // wave-uniform -> s_load, off the LDS pipe
                const float w1 = W2[dd * 3 + 1];
                const float w2 = W2[dd * 3 + 2];
                const float av0 = (q == 0) ? a0.x : (q == 1) ? a0.y : (q == 2) ? a0.z : a0.w;
                const float av1 = (q == 0) ? a1.x : (q == 1) ? a1.y : (q == 2) ? a1.z : a1.w;
                const float bv0 = (q == 0) ? b0.x : (q == 1) ? b0.y : (q == 2) ? b0.z : b0.w;
                const float bv1 = (q == 0) ? b1.x : (q == 1) ? b1.y : (q == 2) ? b1.z : b1.w;
                const float g00 = fast_gelu(av0 + bv0);
                const float g01 = fast_gelu(av0 + bv1);
                const float g10 = fast_gelu(av1 + bv0);
                const float g11 = fast_gelu(av1 + bv1);
                l[0][0] = fmaf(g00, w0, l[0][0]); l[0][1] = fmaf(g00, w1, l[0][1]); l[0][2] = fmaf(g00, w2, l[0][2]);
                l[1][0] = fmaf(g01, w0, l[1][0]); l[1][1] = fmaf(g01, w1, l[1][1]); l[1][2] = fmaf(g01, w2, l[1][2]);
                l[2][0] = fmaf(g10, w0, l[2][0]); l[2][1] = fmaf(g10, w1, l[2][1]); l[2][2] = fmaf(g10, w2, l[2][2]);
                l[3][0] = fmaf(g11, w0, l[3][0]); l[3][1] = fmaf(g11, w1, l[3][1]); l[3][2] = fmaf(g11, w2, l[3][2]);
            }
        }
    }

#pragma unroll
    for (int p = 0; p < 4; ++p) {
        const int i = bi + ty + ((p & 2) ? 16 : 0);
        const int j = bj + tx + ((p & 1) ? 16 : 0);
        const float mm = fmaxf(l[p][0], fmaxf(l[p][1], l[p][2]));
        const float e0 = __expf(l[p][0] - mm), e1 = __expf(l[p][1] - mm), e2 = __expf(l[p][2] - mm);
        const float inv2 = 1.0f / (e0 + e1 + e2);
        float* o = out + ((size_t)i * N + j) * 3;
        o[0] = e0 * inv2; o[1] = e1 * inv2; o[2] = e2 * inv2;
    }
}

extern "C" void kernel_launch(void* const* d_in, const int* in_sizes, int n_in,
                              void* d_out, int out_size, void* d_ws, size_t ws_size,
                              hipStream_t stream)
{
    const float* z    = (const float*)d_in[0];
    const float* dist = (const float*)d_in[1];
    const float* Wq   = (const float*)d_in[2];
    const float* bq   = (const float*)d_in[3];
    const float* Wk   = (const float*)d_in[4];
    const float* bk   = (const float*)d_in[5];
    const float* W1   = (const float*)d_in[6];
    const float* b1   = (const float*)d_in[7];
    const float* W2   = (const float*)d_in[8];
    const float* b2   = (const float*)d_in[9];

    float* out = (float*)d_out;
    float* ws  = (float*)d_ws;
    float* Q  = ws;
    float* K  = ws + (size_t)N * D;
    float* A  = ws + 2 * (size_t)N * D;
    float* B  = ws + 3 * (size_t)N * D;

    proj_kernel<<<N / 8, 256, 0, stream>>>(z, Wq, bq, Wk, bk, W1, b1, Q, K, A, B);
    score_kernel<<<dim3(N / 32, N / 32), 256, 0, stream>>>(Q, K, dist, out);
    topk_kernel<<<N / 4, 256, 0, stream>>>(out);
    pair_kernel<<<dim3(N / 32, N / 32), 256, 0, stream>>>(A, B, W2, b2, out + (size_t)N * N);
}